// Round 8
// baseline (20003.540 us; speedup 1.0000x reference)
//
#include <hip/hip_runtime.h>
#include <cstddef>

// SchNet fwd energy + force bwd, MI355X. Round 8: f32 OUTPUTS (root cause of
// R1-R7 failures: d_out is float32, we were writing packed bf16). f32 inputs,
// general gather/scatter pipeline (R5), fp32 compute.

#define FD     128
#define NRBF   20
#define CUTF   5.0f
#define PI_F   3.14159265358979f

typedef unsigned int u32;

__device__ __forceinline__ float sspf(float x){ return fmaxf(x,0.f)+log1pf(expf(-fabsf(x)))-0.6931471805599453f; }
__device__ __forceinline__ float sigf(float x){ return 1.f/(1.f+expf(-x)); }
__device__ __forceinline__ float fcutf(float d){ return (d < CUTF) ? 0.5f*(cosf(PI_F*d/CUTF)+1.f) : 0.f; }

__global__ __launch_bounds__(256) void k_zero(float* __restrict__ p, int n){
  int i = blockIdx.x*256 + threadIdx.x;
  if(i < n) p[i] = 0.f;
}

__global__ __launch_bounds__(256) void k_embed(const float* __restrict__ emb, const int* __restrict__ Z,
                                               float* __restrict__ X0, int n){
  int idx = blockIdx.x*256 + threadIdx.x;
  if(idx >= n) return;
  int a = idx >> 7, f = idx & 127;
  X0[idx] = emb[Z[a]*FD + f];
}

__global__ __launch_bounds__(256) void k_edge_geom(const float* __restrict__ pos,
    const int* __restrict__ Ii, const int* __restrict__ Ij,
    float* __restrict__ De, float* __restrict__ DBe, int E){
  int e = blockIdx.x*256 + threadIdx.x;
  if(e >= E) return;
  int i = Ii[e], j = Ij[e];
  float dx = pos[j*3+0]-pos[i*3+0];
  float dy = pos[j*3+1]-pos[i*3+1];
  float dz = pos[j*3+2]-pos[i*3+2];
  De[e] = sqrtf(dx*dx+dy*dy+dz*dz + 1e-12f);
  DBe[e] = 0.f;
}

// out = act(A@B(^T) + bias + res) * mul ; rows guarded by Nr.
__global__ __launch_bounds__(256) void k_gemm32(const float* __restrict__ A, const float* __restrict__ B,
    const float* __restrict__ bias, const float* __restrict__ res,
    const float* __restrict__ mul, float* __restrict__ out1, float* __restrict__ out2,
    int transB, int act, int Nr){
  __shared__ float As[64*132];
  const int tid = threadIdx.x;
  const int rb = blockIdx.x * 64;
  for(int q=0;q<8;q++){
    int e = q*256 + tid;
    int r = e >> 5, c = (e & 31) * 4;
    int rr = rb + r; if(rr >= Nr) rr = Nr-1;
    *(float4*)&As[r*132 + c] = *(const float4*)(A + (size_t)rr*FD + c);
  }
  __syncthreads();
  const int r0 = (tid >> 4) * 4;
  const int f0 = (tid & 15) * 8;
  float acc[4][8] = {};
  if(!transB){
    for(int k=0;k<128;k++){
      float a[4] = {As[(r0+0)*132+k], As[(r0+1)*132+k], As[(r0+2)*132+k], As[(r0+3)*132+k]};
      float4 b0 = *(const float4*)(B + k*FD + f0);
      float4 b1 = *(const float4*)(B + k*FD + f0 + 4);
      float b[8] = {b0.x,b0.y,b0.z,b0.w,b1.x,b1.y,b1.z,b1.w};
      #pragma unroll
      for(int i=0;i<4;i++)
        #pragma unroll
        for(int j=0;j<8;j++) acc[i][j] += a[i]*b[j];
    }
  } else {
    for(int k=0;k<128;k++){
      float a[4] = {As[(r0+0)*132+k], As[(r0+1)*132+k], As[(r0+2)*132+k], As[(r0+3)*132+k]};
      float b[8];
      #pragma unroll
      for(int j=0;j<8;j++) b[j] = B[(size_t)(f0+j)*FD + k];
      #pragma unroll
      for(int i=0;i<4;i++)
        #pragma unroll
        for(int j=0;j<8;j++) acc[i][j] += a[i]*b[j];
    }
  }
  float bv[8];
  #pragma unroll
  for(int j=0;j<8;j++) bv[j] = bias ? bias[f0+j] : 0.f;
  #pragma unroll
  for(int rr=0;rr<4;rr++){
    int row = rb + r0 + rr;
    if(row >= Nr) break;
    size_t base = (size_t)row*FD + f0;
    float y[8];
    #pragma unroll
    for(int j=0;j<8;j++) y[j] = acc[rr][j] + bv[j];
    if(res){
      float4 r1 = *(const float4*)(res+base);
      float4 r2 = *(const float4*)(res+base+4);
      y[0]+=r1.x; y[1]+=r1.y; y[2]+=r1.z; y[3]+=r1.w;
      y[4]+=r2.x; y[5]+=r2.y; y[6]+=r2.z; y[7]+=r2.w;
    }
    if(mul){
      float4 m1 = *(const float4*)(mul+base);
      float4 m2 = *(const float4*)(mul+base+4);
      y[0]*=m1.x; y[1]*=m1.y; y[2]*=m1.z; y[3]*=m1.w;
      y[4]*=m2.x; y[5]*=m2.y; y[6]*=m2.z; y[7]*=m2.w;
    }
    if(act){
      *(float4*)(out1+base)   = make_float4(sspf(y[0]),sspf(y[1]),sspf(y[2]),sspf(y[3]));
      *(float4*)(out1+base+4) = make_float4(sspf(y[4]),sspf(y[5]),sspf(y[6]),sspf(y[7]));
      *(float4*)(out2+base)   = make_float4(sigf(y[0]),sigf(y[1]),sigf(y[2]),sigf(y[3]));
      *(float4*)(out2+base+4) = make_float4(sigf(y[4]),sigf(y[5]),sigf(y[6]),sigf(y[7]));
    } else {
      *(float4*)(out1+base)   = make_float4(y[0],y[1],y[2],y[3]);
      *(float4*)(out1+base+4) = make_float4(y[4],y[5],y[6],y[7]);
    }
  }
}

// Edge forward: 4 edges/block, 64 lanes/edge, 2 f per lane.
__global__ __launch_bounds__(256) void k_edge_fwd(
    const float* __restrict__ h,
    const int* __restrict__ Ii, const int* __restrict__ Ij,
    const float* __restrict__ De,
    const float* __restrict__ W1, const float* __restrict__ b1,
    const float* __restrict__ W2, const float* __restrict__ b2,
    float* __restrict__ agg, int E){
  __shared__ float srbf[4][NRBF];
  __shared__ float sP[4][128];
  const int tid = threadIdx.x;
  const int e4 = tid >> 6, lane = tid & 63;
  const int e = blockIdx.x*4 + e4;
  const bool ok = (e < E);
  const float step = CUTF/19.0f;
  const float coef = -0.5f/(step*step);
  if(tid < 4*NRBF){
    int ee = blockIdx.x*4 + tid/NRBF, k = tid%NRBF;
    if(ee < E){
      float x = De[ee] - step*(float)k;
      srbf[tid/NRBF][k] = expf(coef*x*x);
    }
  }
  __syncthreads();
  int i=0, j=0; float fc=0.f;
  if(ok){ i = Ii[e]; j = Ij[e]; fc = fcutf(De[e]); }
  const int f0 = lane, f1 = lane + 64;
  if(ok){
    float t0 = b1[f0], t1 = b1[f1];
    #pragma unroll
    for(int k=0;k<NRBF;k++){
      float r = srbf[e4][k];
      t0 += r*W1[k*FD + f0];
      t1 += r*W1[k*FD + f1];
    }
    sP[e4][f0] = sspf(t0);
    sP[e4][f1] = sspf(t1);
  }
  __syncthreads();
  if(ok){
    float w0 = b2[f0], w1 = b2[f1];
    for(int c=0;c<128;c++){
      float p = sP[e4][c];
      w0 += p*W2[c*FD + f0];
      w1 += p*W2[c*FD + f1];
    }
    atomicAdd(&agg[(size_t)i*FD + f0], h[(size_t)j*FD + f0] * w0 * fc);
    atomicAdd(&agg[(size_t)i*FD + f1], h[(size_t)j*FD + f1] * w1 * fc);
  }
}

// Edge backward: 4 edges/block.
__global__ __launch_bounds__(256) void k_edge_bwd(
    const float* __restrict__ h, const float* __restrict__ AB,
    const int* __restrict__ Ii, const int* __restrict__ Ij,
    const float* __restrict__ De,
    const float* __restrict__ W1, const float* __restrict__ b1,
    const float* __restrict__ W2, const float* __restrict__ b2,
    float* __restrict__ DBe, float* __restrict__ HB, int E){
  __shared__ float srbf[4][NRBF];
  __shared__ float sP[4][128];
  __shared__ float sSig[4][128];
  __shared__ float sWb[4][128];
  __shared__ float sTb[4][128];
  __shared__ float sfb[4];
  __shared__ float sterm[4][NRBF];
  const int tid = threadIdx.x;
  const int e4 = tid >> 6, lane = tid & 63;
  const int e = blockIdx.x*4 + e4;
  const bool ok = (e < E);
  const float step = CUTF/19.0f;
  const float coef = -0.5f/(step*step);
  if(tid < 4*NRBF){
    int ee = blockIdx.x*4 + tid/NRBF, k = tid%NRBF;
    if(ee < E){
      float x = De[ee] - step*(float)k;
      srbf[tid/NRBF][k] = expf(coef*x*x);
    }
  }
  __syncthreads();
  int i=0, j=0; float fc=0.f;
  if(ok){ i = Ii[e]; j = Ij[e]; fc = fcutf(De[e]); }
  const int f0 = lane, f1 = lane + 64;
  if(ok){
    float t0 = b1[f0], t1 = b1[f1];
    #pragma unroll
    for(int k=0;k<NRBF;k++){
      float r = srbf[e4][k];
      t0 += r*W1[k*FD + f0];
      t1 += r*W1[k*FD + f1];
    }
    sP[e4][f0] = sspf(t0);  sSig[e4][f0] = sigf(t0);
    sP[e4][f1] = sspf(t1);  sSig[e4][f1] = sigf(t1);
  }
  __syncthreads();
  if(ok){
    float w0 = b2[f0], w1 = b2[f1];
    for(int c=0;c<128;c++){
      float p = sP[e4][c];
      w0 += p*W2[c*FD + f0];
      w1 += p*W2[c*FD + f1];
    }
    float a0 = AB[(size_t)i*FD + f0], a1 = AB[(size_t)i*FD + f1];
    float h0 = h [(size_t)j*FD + f0], h1 = h [(size_t)j*FD + f1];
    atomicAdd(&HB[(size_t)j*FD + f0], a0*w0*fc);
    atomicAdd(&HB[(size_t)j*FD + f1], a1*w1*fc);
    sWb[e4][f0] = a0*h0*fc;
    sWb[e4][f1] = a1*h1*fc;
    float pf = a0*h0*w0 + a1*h1*w1;
    #pragma unroll
    for(int s=1; s<64; s<<=1) pf += __shfl_xor(pf, s);
    if(lane == 0) sfb[e4] = pf;
  }
  __syncthreads();
  if(ok){
    const int c0 = lane, c1 = lane + 64;
    float p0 = 0.f, p1 = 0.f;
    for(int f=0; f<128; f++){
      float wb = sWb[e4][f];
      p0 += wb * W2[c0*FD + f];
      p1 += wb * W2[c1*FD + f];
    }
    sTb[e4][c0] = p0 * sSig[e4][c0];
    sTb[e4][c1] = p1 * sSig[e4][c1];
  }
  __syncthreads();
  if(tid < 4*NRBF){
    int le = tid/NRBF, k = tid%NRBF;
    int ee = blockIdx.x*4 + le;
    if(ee < E){
      float rk = 0.f;
      for(int c=0;c<128;c++) rk += sTb[le][c] * W1[k*FD + c];
      float x = De[ee] - step*(float)k;
      sterm[le][k] = rk * srbf[le][k] * 2.f*coef*x;
    }
  }
  __syncthreads();
  if(tid < 4){
    int ee = blockIdx.x*4 + tid;
    if(ee < E){
      float dd = De[ee];
      float v = 0.f;
      #pragma unroll
      for(int k=0;k<NRBF;k++) v += sterm[tid][k];
      float dfc = (dd < CUTF) ? (-0.5f*(PI_F/CUTF)*sinf(PI_F*dd/CUTF)) : 0.f;
      DBe[ee] += v + sfb[tid]*dfc;
    }
  }
}

// fused atomwise head + head-backward. block = 64 atoms (rows guarded).
__global__ __launch_bounds__(256) void k_head(const float* __restrict__ X3,
    const float* __restrict__ aW1, const float* __restrict__ ab1,
    const float* __restrict__ aW2, const float* __restrict__ ab2,
    const int* __restrict__ mol, float* __restrict__ Emol, float* __restrict__ XB, int N){
  __shared__ float sx[64*129];
  __shared__ float sg[64*65];
  const int tid = threadIdx.x;
  const int base = blockIdx.x*64;
  for(int q=0;q<8;q++){
    int ee = q*256 + tid;
    int r = ee >> 5, c = (ee & 31)*4;
    int row = base + r; if(row >= N) row = N-1;
    float4 v = *(const float4*)(X3 + (size_t)row*FD + c);
    sx[r*129 + c+0] = v.x; sx[r*129 + c+1] = v.y;
    sx[r*129 + c+2] = v.z; sx[r*129 + c+3] = v.w;
  }
  __syncthreads();
  {
    const int a = tid >> 2, q = tid & 3;
    float pe = 0.f;
    for(int cc=0; cc<16; cc++){
      int c = q*16 + cc;
      float u = ab1[c];
      for(int f=0; f<128; f++) u += sx[a*129 + f]*aW1[f*64 + c];
      pe += sspf(u)*aW2[c];
      sg[a*65 + c] = sigf(u)*aW2[c];
    }
    pe += __shfl_xor(pe, 1);
    pe += __shfl_xor(pe, 2);
    if(q == 0 && base + a < N) atomicAdd(&Emol[mol[base + a]], pe + ab2[0]);
  }
  __syncthreads();
  {
    const int f = tid & 127, g2 = tid >> 7;
    float acc[32];
    #pragma unroll
    for(int q=0;q<32;q++) acc[q]=0.f;
    for(int c=0;c<64;c++){
      float w = aW1[f*64 + c];
      #pragma unroll
      for(int q=0;q<32;q++) acc[q] += sg[(g2*32+q)*65 + c]*w;
    }
    #pragma unroll
    for(int q=0;q<32;q++){
      int row = base + g2*32 + q;
      if(row < N) XB[(size_t)row*FD + f] = acc[q];
    }
  }
}

__global__ __launch_bounds__(256) void k_grad(const float* __restrict__ pos,
    const int* __restrict__ Ii, const int* __restrict__ Ij,
    const float* __restrict__ De, const float* __restrict__ DBe,
    float* __restrict__ G, int E){
  int e = blockIdx.x*256 + threadIdx.x;
  if(e >= E) return;
  float s = DBe[e] / De[e];
  int i = Ii[e], j = Ij[e];
  float dx = s*(pos[i*3+0]-pos[j*3+0]);
  float dy = s*(pos[i*3+1]-pos[j*3+1]);
  float dz = s*(pos[i*3+2]-pos[j*3+2]);
  atomicAdd(&G[i*3+0], dx); atomicAdd(&G[i*3+1], dy); atomicAdd(&G[i*3+2], dz);
  atomicAdd(&G[j*3+0], -dx); atomicAdd(&G[j*3+1], -dy); atomicAdd(&G[j*3+2], -dz);
}

__global__ __launch_bounds__(256) void k_norm(const float* __restrict__ G,
    const int* __restrict__ mol, u32* __restrict__ maxnU, int N){
  int n = blockIdx.x*256 + threadIdx.x;
  if(n >= N) return;
  float ax = G[n*3], ay = G[n*3+1], az = G[n*3+2];
  float nrm = sqrtf(ax*ax+ay*ay+az*az);
  atomicMax(&maxnU[mol[n]], __float_as_uint(nrm));
}

// action (f32) = -G * per-molecule clip coef
__global__ __launch_bounds__(256) void k_apply(const float* __restrict__ G,
    const int* __restrict__ mol, const u32* __restrict__ maxnU,
    float* __restrict__ outA, int N){
  int n = blockIdx.x*256 + threadIdx.x;
  if(n >= N) return;
  float mx = __uint_as_float(maxnU[mol[n]]);
  float coefc = fminf(1.0f/fmaxf(mx, 1e-8f), 1.0f);
  outA[n*3+0] = -G[n*3+0]*coefc;
  outA[n*3+1] = -G[n*3+1]*coefc;
  outA[n*3+2] = -G[n*3+2]*coefc;
}

extern "C" void kernel_launch(void* const* d_in, const int* in_sizes, int n_in,
                              void* d_out, int out_size, void* d_ws, size_t ws_size,
                              hipStream_t stream) {
  (void)n_in;
  const float* pos  = (const float*)d_in[0];
  const float* emb  = (const float*)d_in[1];
  const float* in2f = (const float*)d_in[2];
  const float* fW1  = (const float*)d_in[3];
  const float* fb1  = (const float*)d_in[4];
  const float* fW2  = (const float*)d_in[5];
  const float* fb2  = (const float*)d_in[6];
  const float* oW1  = (const float*)d_in[7];
  const float* ob1  = (const float*)d_in[8];
  const float* oW2  = (const float*)d_in[9];
  const float* ob2  = (const float*)d_in[10];
  const float* aW1  = (const float*)d_in[11];
  const float* ab1  = (const float*)d_in[12];
  const float* aW2  = (const float*)d_in[13];
  const float* ab2  = (const float*)d_in[14];
  const int*   Z    = (const int*)d_in[15];
  const int*   Ii   = (const int*)d_in[16];
  const int*   Ij   = (const int*)d_in[17];
  const int*   mol  = (const int*)d_in[18];
  const int N = in_sizes[15];
  const int E = in_sizes[16];
  const int M = out_size - N*3;
  const size_t NFE = (size_t)N*FD;
  float* outF = (float*)d_out;         // [N*3 action][M energy], f32
  float* outE = outF + (size_t)N*3;
  float* ws = (float*)d_ws;
  if(ws_size < (11*NFE + 2*(size_t)E)*4) return;

  float* X0  = ws;                     // x_l: 4 buffers
  float* SV0 = ws + 4*NFE;             // sigma(v_l): 3
  float* H   = ws + 7*NFE;
  float* AGG = ws + 8*NFE;
  float* XB  = ws + 9*NFE;
  float* HB  = ws + 10*NFE;
  float* De  = ws + 11*NFE;
  float* DBe = De + E;
  float* G    = AGG;                   // after bwd loop
  u32*  maxnU = (u32*)H;               // after bwd loop

  const int gN   = (int)((NFE + 255)/256);
  const int gE   = (E + 255)/256;
  const int gE4  = (E + 3)/4;
  const int gRow = (N + 63)/64;

  k_embed<<<gN,256,0,stream>>>(emb, Z, X0, (int)NFE);
  k_edge_geom<<<gE,256,0,stream>>>(pos, Ii, Ij, De, DBe, E);
  for(int l=0;l<3;l++){
    float* Xl  = X0 + (size_t)l*NFE;
    float* Xn  = X0 + (size_t)(l+1)*NFE;
    float* SVl = SV0 + (size_t)l*NFE;
    k_gemm32<<<gRow,256,0,stream>>>(Xl, in2f + l*16384, nullptr, nullptr, nullptr, H, nullptr, 0, 0, N);
    k_zero<<<gN,256,0,stream>>>(AGG, (int)NFE);
    k_edge_fwd<<<gE4,256,0,stream>>>(H, Ii, Ij, De, fW1 + l*2560, fb1 + l*128, fW2 + l*16384, fb2 + l*128, AGG, E);
    k_gemm32<<<gRow,256,0,stream>>>(AGG, oW1 + l*16384, ob1 + l*128, nullptr, nullptr, H, SVl, 0, 1, N);
    k_gemm32<<<gRow,256,0,stream>>>(H, oW2 + l*16384, ob2 + l*128, Xl, nullptr, Xn, nullptr, 0, 0, N);
  }
  k_zero<<<(M+255)/256,256,0,stream>>>(outE, M);
  k_head<<<gRow,256,0,stream>>>(X0 + 3*NFE, aW1, ab1, aW2, ab2, mol, outE, XB, N);
  for(int l=2;l>=0;l--){
    float* Xl  = X0 + (size_t)l*NFE;
    float* SVl = SV0 + (size_t)l*NFE;
    k_gemm32<<<gRow,256,0,stream>>>(XB, oW2 + l*16384, nullptr, nullptr, SVl, AGG, nullptr, 1, 0, N);
    k_gemm32<<<gRow,256,0,stream>>>(AGG, oW1 + l*16384, nullptr, nullptr, nullptr, AGG, nullptr, 1, 0, N);
    k_gemm32<<<gRow,256,0,stream>>>(Xl, in2f + l*16384, nullptr, nullptr, nullptr, H, nullptr, 0, 0, N);
    k_zero<<<gN,256,0,stream>>>(HB, (int)NFE);
    k_edge_bwd<<<gE4,256,0,stream>>>(H, AGG, Ii, Ij, De, fW1 + l*2560, fb1 + l*128, fW2 + l*16384, fb2 + l*128, DBe, HB, E);
    k_gemm32<<<gRow,256,0,stream>>>(HB, in2f + l*16384, nullptr, XB, nullptr, XB, nullptr, 1, 0, N);
  }
  k_zero<<<(N*3+255)/256,256,0,stream>>>(G, N*3);
  k_zero<<<(M+255)/256,256,0,stream>>>((float*)maxnU, M);
  k_grad<<<gE,256,0,stream>>>(pos, Ii, Ij, De, DBe, G, E);
  k_norm<<<(N+255)/256,256,0,stream>>>(G, mol, maxnU, N);
  k_apply<<<(N+255)/256,256,0,stream>>>(G, mol, maxnU, outF, N);
}